// Round 10
// baseline (119.274 us; speedup 1.0000x reference)
//
#include <hip/hip_runtime.h>

// Fused persistent kernel — r7 topology + J double-buffer prefetch +
// chunk-granular incremental fanout/consume.
// 14-step recurrence, N=1680:
//   temp = J @ r_{t-1};  U = temp + Iext;  sq = (0.2U)^2
//   recSum = 0.005*sum(sq);  r_t = sq/recSum
// Invariant: carry unnormalized r̃_t = sq_t;  s_t = 0.005*sum(r̃_t);
//   J @ r_{t-1} = (J @ r̃_{t-1}) / s_{t-1}.
//
// Protocol (data IS the barrier): 14 per-step buffers of 420 quads in ws,
// sentinel-filled 0xBF (-1.498f < 0) per launch; quad valid iff all 4
// elems >= 0 (sq is a square; every element checked -> tear-safe).
//
// Round-10 changes (post-arrival chain was ~1400cy of the 3.5us step):
//  1. J ping-pong prefetch: step t+1's 28 J loads issued at END of step t
//     (asm defs, no waitcnt) -> land during publish+spin; consume-time
//     drain ~0. Static even/odd unroll (JA/JB), no runtime indexing.
//  2. Chunk fanout: poller ds_writes each quad as it validates, sets 7
//     per-chunk LDS flags (chunk k complete when __all lanes did slot k),
//     FMAs its own rows during the poll (free under pass latency).
//     Producers spin+consume chunk-by-chunk: 6/7 of the dot done before
//     the last quad lands. Post-arrival chain = 16 FMA + butterfly +
//     publish (~300cy).

typedef float f32x4 __attribute__((ext_vector_type(4)));

#define N      1680
#define NV4    420          // N/4
#define NSTEP  14
#define GBLK   105          // blocks; 105*16 = 1680 rows
#define RPB    16           // rows per block
#define RPW    4            // rows per wave

// Issue 7 cached loads as asm defs, NO waitcnt (prefetch; drain later).
__device__ __forceinline__ void jload7_issue(
    const f32x4* p0, const f32x4* p1, const f32x4* p2, const f32x4* p3,
    const f32x4* p4, const f32x4* p5, const f32x4* p6,
    f32x4& v0, f32x4& v1, f32x4& v2, f32x4& v3,
    f32x4& v4, f32x4& v5, f32x4& v6)
{
    asm volatile(
        "global_load_dwordx4 %0, %7, off\n\t"
        "global_load_dwordx4 %1, %8, off\n\t"
        "global_load_dwordx4 %2, %9, off\n\t"
        "global_load_dwordx4 %3, %10, off\n\t"
        "global_load_dwordx4 %4, %11, off\n\t"
        "global_load_dwordx4 %5, %12, off\n\t"
        "global_load_dwordx4 %6, %13, off"
        : "=&v"(v0), "=&v"(v1), "=&v"(v2), "=&v"(v3),
          "=&v"(v4), "=&v"(v5), "=&v"(v6)
        : "v"(p0), "v"(p1), "v"(p2), "v"(p3), "v"(p4), "v"(p5), "v"(p6));
}

// Drain all vmem; fence the scheduler so uses can't hoist above (rule #18).
__device__ __forceinline__ void vm_wait0() {
    asm volatile("s_waitcnt vmcnt(0)" ::: "memory");
    __builtin_amdgcn_sched_barrier(0);
}

// 7 LLC-coherent loads (bypass L1/L2), one vmcnt drain.
__device__ __forceinline__ void load7_llc(
    const f32x4* p0, const f32x4* p1, const f32x4* p2, const f32x4* p3,
    const f32x4* p4, const f32x4* p5, const f32x4* p6,
    f32x4& v0, f32x4& v1, f32x4& v2, f32x4& v3,
    f32x4& v4, f32x4& v5, f32x4& v6)
{
    asm volatile(
        "global_load_dwordx4 %0, %7, off sc0 sc1\n\t"
        "global_load_dwordx4 %1, %8, off sc0 sc1\n\t"
        "global_load_dwordx4 %2, %9, off sc0 sc1\n\t"
        "global_load_dwordx4 %3, %10, off sc0 sc1\n\t"
        "global_load_dwordx4 %4, %11, off sc0 sc1\n\t"
        "global_load_dwordx4 %5, %12, off sc0 sc1\n\t"
        "global_load_dwordx4 %6, %13, off sc0 sc1\n\t"
        "s_waitcnt vmcnt(0)"
        : "=&v"(v0), "=&v"(v1), "=&v"(v2), "=&v"(v3),
          "=&v"(v4), "=&v"(v5), "=&v"(v6)
        : "v"(p0), "v"(p1), "v"(p2), "v"(p3), "v"(p4), "v"(p5), "v"(p6)
        : "memory");
}

__device__ __forceinline__ void llc_store4(f32x4* p, f32x4 v) {
    asm volatile("global_store_dwordx4 %0, %1, off sc0 sc1"
                 :: "v"(p), "v"(v) : "memory");
}

__global__ __launch_bounds__(256, 1) void fused_recur(
    const float* __restrict__ J,
    const float* __restrict__ net_in,     // [0,N): Iext ; [N,2N): r0
    float* __restrict__ out,              // U_13 (N) | recSum_13 (1) | r_13 (N)
    float* __restrict__ ws)               // 14 * 420 f32x4, sentinel-filled
{
    __shared__ f32x4 lds_r[2][NV4];       // parity double-buffer of r̃
    __shared__ float lds_flag[NSTEP][8];  // [buf t][chunk k], k=0..6

    f32x4* bufs = (f32x4*)ws;

    const int tid  = threadIdx.x;
    const int lane = tid & 63;
    const int wave = tid >> 6;
    const int row0 = (int)blockIdx.x * RPB + wave * RPW;

    // lanes >= 36 have no slot 6 (only 420 quads); q6 addr clamps to quad 0.
    const unsigned pend0 = (lane < 36) ? 0x7Fu : 0x3Fu;

    if (tid < NSTEP * 8) ((float*)lds_flag)[tid] = 0.0f;
    __syncthreads();                      // one-time init (only block barrier)

    float iext[RPW];
    #pragma unroll
    for (int m = 0; m < RPW; ++m) iext[m] = net_in[row0 + m];

    const f32x4* jb[RPW];
    #pragma unroll
    for (int m = 0; m < RPW; ++m)
        jb[m] = (const f32x4*)(J + (size_t)(row0 + m) * N);

    f32x4 JA[RPW][7], JB[RPW][7];
    // prologue: issue J(0) into JA
    #pragma unroll
    for (int m = 0; m < RPW; ++m)
        jload7_issue(jb[m] + lane,       jb[m] + lane + 64,
                     jb[m] + lane + 128, jb[m] + lane + 192,
                     jb[m] + lane + 256, jb[m] + lane + 320,
                     (lane < 36) ? (jb[m] + lane + 384) : jb[m],
                     JA[m][0], JA[m][1], JA[m][2], JA[m][3],
                     JA[m][4], JA[m][5], JA[m][6]);

    float Uv[RPW], Qv[RPW];

    // butterfly + outputs + publish + prefetch-next (shared step tail)
    auto step_tail = [&](int t, float red[5], f32x4 (&Jnxt)[RPW][7]) {
        #pragma unroll
        for (int off = 32; off; off >>= 1) {
            #pragma unroll
            for (int i = 0; i < 5; ++i) red[i] += __shfl_xor(red[i], off, 64);
        }
        const float inv = (t == 0) ? 1.0f : 1.0f / (0.005f * red[4]);
        #pragma unroll
        for (int m = 0; m < RPW; ++m) {
            const float U  = red[m] * inv + iext[m];    // ALPHA=BETA=1
            const float u2 = 0.2f * U;
            Uv[m] = U;
            Qv[m] = u2 * u2;                            // sq >= 0 always
        }
        if (lane == 0) {
            f32x4 pub = { Qv[0], Qv[1], Qv[2], Qv[3] };
            llc_store4(bufs + (size_t)t * NV4 + (row0 >> 2), pub);
        }
        if (t + 1 < NSTEP) {               // prefetch next step's J rows
            #pragma unroll
            for (int m = 0; m < RPW; ++m)
                jload7_issue(jb[m] + lane,       jb[m] + lane + 64,
                             jb[m] + lane + 128, jb[m] + lane + 192,
                             jb[m] + lane + 256, jb[m] + lane + 320,
                             (lane < 36) ? (jb[m] + lane + 384) : jb[m],
                             Jnxt[m][0], Jnxt[m][1], Jnxt[m][2], Jnxt[m][3],
                             Jnxt[m][4], Jnxt[m][5], Jnxt[m][6]);
        }
    };

    // ---- t = 0: r0 from net_in, s_{-1} = 1 ----
    {
        vm_wait0();                        // JA resident
        const f32x4* r0 = (const f32x4*)(net_in + N);
        f32x4 acc[RPW];
        #pragma unroll
        for (int m = 0; m < RPW; ++m) acc[m] = (f32x4)0.f;
        float psum = 0.0f;
        #pragma unroll
        for (int k = 0; k < 7; ++k) {
            const int idx = lane + 64 * k;
            const f32x4 q = (idx < NV4) ? r0[idx] : (f32x4)0.f;
            #pragma unroll
            for (int m = 0; m < RPW; ++m) {
                acc[m][0] += JA[m][k][0] * q[0];
                acc[m][1] += JA[m][k][1] * q[1];
                acc[m][2] += JA[m][k][2] * q[2];
                acc[m][3] += JA[m][k][3] * q[3];
            }
            psum += (q[0] + q[1]) + (q[2] + q[3]);
        }
        float red[5];
        #pragma unroll
        for (int m = 0; m < RPW; ++m)
            red[m] = (acc[m][0] + acc[m][1]) + (acc[m][2] + acc[m][3]);
        red[4] = psum;
        step_tail(0, red, JB);
    }

    // ---- generic step body (t >= 1), static Jcur/Jnxt binding ----
    auto step_body = [&](int t, f32x4 (&Jcur)[RPW][7], f32x4 (&Jnxt)[RPW][7]) {
        const int par = (t - 1) & 1;
        f32x4 acc[RPW];
        #pragma unroll
        for (int m = 0; m < RPW; ++m) acc[m] = (f32x4)0.f;
        float psum = 0.0f;

        if (wave == 0) {
            // poller: incremental poll -> ds_write + own-row FMA + chunk flags
            const f32x4* base = bufs + (size_t)(t - 1) * NV4;
            const f32x4* q0 = base + lane;
            const f32x4* q1 = base + lane + 64;
            const f32x4* q2 = base + lane + 128;
            const f32x4* q3 = base + lane + 192;
            const f32x4* q4 = base + lane + 256;
            const f32x4* q5 = base + lane + 320;
            const f32x4* q6 = (lane < 36) ? (base + lane + 384) : base;

            unsigned pend = pend0, fleft = 0x7Fu;
            #pragma unroll 1
            for (;;) {
                f32x4 rv[7];
                load7_llc(q0, q1, q2, q3, q4, q5, q6,   // drains Jcur too
                          rv[0], rv[1], rv[2], rv[3], rv[4], rv[5], rv[6]);
                #pragma unroll
                for (int k = 0; k < 7; ++k) {
                    if ((pend >> k) & 1u) {
                        const f32x4 q = rv[k];
                        const float mn = fminf(fminf(q[0], q[1]),
                                               fminf(q[2], q[3]));
                        if (mn >= 0.0f) {
                            lds_r[par][lane + 64 * k] = q;
                            #pragma unroll
                            for (int m = 0; m < RPW; ++m) {
                                acc[m][0] += Jcur[m][k][0] * q[0];
                                acc[m][1] += Jcur[m][k][1] * q[1];
                                acc[m][2] += Jcur[m][k][2] * q[2];
                                acc[m][3] += Jcur[m][k][3] * q[3];
                            }
                            psum += (q[0] + q[1]) + (q[2] + q[3]);
                            pend &= ~(1u << k);
                        }
                    }
                }
                #pragma unroll
                for (int k = 0; k < 7; ++k) {
                    if ((fleft >> k) & 1u) {
                        if (__all(((pend >> k) & 1u) == 0u)) {
                            if (lane == 0)   // release: lgkmcnt covers ds_writes
                                __hip_atomic_store(&lds_flag[t - 1][k], 1.0f,
                                                   __ATOMIC_RELEASE,
                                                   __HIP_MEMORY_SCOPE_WORKGROUP);
                            fleft &= ~(1u << k);
                        }
                    }
                }
                if (!__any(pend != 0u)) break;
            }
        } else {
            // producer: chunk-by-chunk spin + consume (J drained at k==0)
            #pragma unroll
            for (int k = 0; k < 7; ++k) {
                while (__hip_atomic_load(&lds_flag[t - 1][k], __ATOMIC_ACQUIRE,
                                         __HIP_MEMORY_SCOPE_WORKGROUP) == 0.0f) {}
                if (k == 0) vm_wait0();     // Jcur landed during prior step
                if (k < 6 || lane < 36) {
                    const f32x4 q = lds_r[par][lane + 64 * k];
                    #pragma unroll
                    for (int m = 0; m < RPW; ++m) {
                        acc[m][0] += Jcur[m][k][0] * q[0];
                        acc[m][1] += Jcur[m][k][1] * q[1];
                        acc[m][2] += Jcur[m][k][2] * q[2];
                        acc[m][3] += Jcur[m][k][3] * q[3];
                    }
                    psum += (q[0] + q[1]) + (q[2] + q[3]);
                }
            }
        }

        float red[5];
        #pragma unroll
        for (int m = 0; m < RPW; ++m)
            red[m] = (acc[m][0] + acc[m][1]) + (acc[m][2] + acc[m][3]);
        red[4] = psum;
        step_tail(t, red, Jnxt);
    };

    // static even/odd unroll: t0 used JA (issued JB); odd t -> JB, even -> JA
    #pragma unroll 1
    for (int tt = 1; tt < NSTEP; tt += 2) {
        step_body(tt, JB, JA);
        if (tt + 1 < NSTEP) step_body(tt + 1, JA, JB);
    }

    // ---- finish: s13 = 0.005 * sum(buf[13]); par = 13&1 = 1 ----
    float s13;
    {
        float psum = 0.0f;
        if (wave == 0) {
            const f32x4* base = bufs + (size_t)(NSTEP - 1) * NV4;
            const f32x4* q0 = base + lane;
            const f32x4* q1 = base + lane + 64;
            const f32x4* q2 = base + lane + 128;
            const f32x4* q3 = base + lane + 192;
            const f32x4* q4 = base + lane + 256;
            const f32x4* q5 = base + lane + 320;
            const f32x4* q6 = (lane < 36) ? (base + lane + 384) : base;
            unsigned pend = pend0, fleft = 0x7Fu;
            #pragma unroll 1
            for (;;) {
                f32x4 rv[7];
                load7_llc(q0, q1, q2, q3, q4, q5, q6,
                          rv[0], rv[1], rv[2], rv[3], rv[4], rv[5], rv[6]);
                #pragma unroll
                for (int k = 0; k < 7; ++k) {
                    if ((pend >> k) & 1u) {
                        const f32x4 q = rv[k];
                        const float mn = fminf(fminf(q[0], q[1]),
                                               fminf(q[2], q[3]));
                        if (mn >= 0.0f) {
                            lds_r[1][lane + 64 * k] = q;
                            psum += (q[0] + q[1]) + (q[2] + q[3]);
                            pend &= ~(1u << k);
                        }
                    }
                }
                #pragma unroll
                for (int k = 0; k < 7; ++k) {
                    if ((fleft >> k) & 1u) {
                        if (__all(((pend >> k) & 1u) == 0u)) {
                            if (lane == 0)
                                __hip_atomic_store(&lds_flag[NSTEP - 1][k], 1.0f,
                                                   __ATOMIC_RELEASE,
                                                   __HIP_MEMORY_SCOPE_WORKGROUP);
                            fleft &= ~(1u << k);
                        }
                    }
                }
                if (!__any(pend != 0u)) break;
            }
        } else {
            #pragma unroll
            for (int k = 0; k < 7; ++k) {
                while (__hip_atomic_load(&lds_flag[NSTEP - 1][k],
                                         __ATOMIC_ACQUIRE,
                                         __HIP_MEMORY_SCOPE_WORKGROUP) == 0.0f) {}
                if (k < 6 || lane < 36) {
                    const f32x4 q = lds_r[1][lane + 64 * k];
                    psum += (q[0] + q[1]) + (q[2] + q[3]);
                }
            }
        }
        #pragma unroll
        for (int off = 32; off; off >>= 1) psum += __shfl_xor(psum, off, 64);
        s13 = 0.005f * psum;
    }

    if (lane == 0) {
        f32x4 u4 = { Uv[0], Uv[1], Uv[2], Uv[3] };
        *(f32x4*)(out + row0) = u4;                     // U_13 (16B aligned)
    }
    if (lane < RPW) {                                   // r_13 (offset N+1: scalar)
        const float q = (lane == 0) ? Qv[0] : (lane == 1) ? Qv[1]
                       : (lane == 2) ? Qv[2] : Qv[3];
        out[N + 1 + row0 + lane] = q / s13;
    }
    if (blockIdx.x == 0 && tid == 0) out[N] = s13;      // recSum_13
}

extern "C" void kernel_launch(void* const* d_in, const int* in_sizes, int n_in,
                              void* d_out, int out_size, void* d_ws, size_t ws_size,
                              hipStream_t stream) {
    const float* net_in = (const float*)d_in[0];   // 2N: Iext | r0
    const float* J      = (const float*)d_in[1];   // N x N row-major
    // Sentinel-fill all 14 step buffers: every byte 0xBF -> -1.498f (< 0).
    hipMemsetAsync(d_ws, 0xBF, (size_t)NSTEP * NV4 * sizeof(f32x4), stream);
    fused_recur<<<GBLK, 256, 0, stream>>>(J, net_in, (float*)d_out, (float*)d_ws);
}